// Round 1
// baseline (1002.126 us; speedup 1.0000x reference)
//
#include <hip/hip_runtime.h>

#define D 128
#define OUTD 64
#define LAYERS 3

static inline int ceil_div(int a, int b) { return (a + b - 1) / b; }

// ---------------- CSR build ----------------

__global__ __launch_bounds__(256)
void count_deg(const int* __restrict__ src, const int* __restrict__ dst, int E,
               int* cnt_out, int* cnt_in) {
    int e = blockIdx.x * 256 + threadIdx.x;
    if (e < E) {
        atomicAdd(&cnt_out[src[e]], 1);
        atomicAdd(&cnt_in[dst[e]], 1);
    }
}

// grid of 2 blocks: block 0 scans cnt_a->row_a, block 1 scans cnt_b->row_b
__global__ __launch_bounds__(1024)
void scan2(const int* __restrict__ cnt_a, int* __restrict__ row_a,
           const int* __restrict__ cnt_b, int* __restrict__ row_b, int n) {
    const int* cnt = blockIdx.x ? cnt_b : cnt_a;
    int* row = blockIdx.x ? row_b : row_a;
    __shared__ int wsum[16];
    __shared__ int chunk_total;
    int lane = threadIdx.x & 63;
    int w = threadIdx.x >> 6;
    int carry = 0;
    for (int base = 0; base < n; base += 1024) {
        int i = base + threadIdx.x;
        int v = (i < n) ? cnt[i] : 0;
        int x = v;
        #pragma unroll
        for (int off = 1; off < 64; off <<= 1) {
            int y = __shfl_up(x, off, 64);
            if (lane >= off) x += y;
        }
        if (lane == 63) wsum[w] = x;
        __syncthreads();
        if (w == 0 && lane < 16) {
            int s = wsum[lane];
            #pragma unroll
            for (int off = 1; off < 16; off <<= 1) {
                int y = __shfl_up(s, off, 16);
                if (lane >= off) s += y;
            }
            wsum[lane] = s;
            if (lane == 15) chunk_total = s;
        }
        __syncthreads();
        int wpre = (w == 0) ? 0 : wsum[w - 1];
        if (i < n) row[i] = carry + wpre + (x - v);   // exclusive scan
        carry += chunk_total;
        __syncthreads();
    }
    if (threadIdx.x == 0) row[n] = carry;
}

__global__ __launch_bounds__(256)
void fill_csr(const int* __restrict__ src, const int* __restrict__ dst, int E,
              const int* __restrict__ row_in, const int* __restrict__ row_out,
              int* cur_in, int* cur_out,
              int* __restrict__ col_in, int* __restrict__ col_out) {
    int e = blockIdx.x * 256 + threadIdx.x;
    if (e < E) {
        int s = src[e], d = dst[e];
        int p = atomicAdd(&cur_in[d], 1);
        col_in[row_in[d] + p] = s;
        int q = atomicAdd(&cur_out[s], 1);
        col_out[row_out[s] + q] = d;
    }
}

// ---------------- GEMM: C{0,1,2} = A @ B{0,1,2}  (A: MxD, B: DxD, C: MxD) ----------------

__global__ __launch_bounds__(256)
void gemm3(const float* __restrict__ A, int M,
           const float* __restrict__ B0, const float* __restrict__ B1, const float* __restrict__ B2,
           float* __restrict__ C0, float* __restrict__ C1, float* __restrict__ C2) {
    __shared__ float As[64][68];
    __shared__ float Bs[64][68];
    int tid = threadIdx.x;
    int tx = tid & 15, ty = tid >> 4;
    int m0 = blockIdx.x * 64;
    int n0 = blockIdx.y * 64;
    const float* B;
    float* C;
    if (blockIdx.z == 0)      { B = B0; C = C0; }
    else if (blockIdx.z == 1) { B = B1; C = C1; }
    else                      { B = B2; C = C2; }

    float acc[4][4] = {{0.f}};
    int r = tid >> 4;    // 0..15
    int kq = tid & 15;   // float4 index

    for (int kt = 0; kt < D; kt += 64) {
        #pragma unroll
        for (int i = 0; i < 4; i++) {
            int row = r + i * 16;
            int gm = m0 + row;
            float4 v = make_float4(0.f, 0.f, 0.f, 0.f);
            if (gm < M) v = *(const float4*)(A + (size_t)gm * D + kt + kq * 4);
            *(float4*)&As[row][kq * 4] = v;
        }
        #pragma unroll
        for (int i = 0; i < 4; i++) {
            int k = r + i * 16;
            *(float4*)&Bs[k][kq * 4] = *(const float4*)(B + (size_t)(kt + k) * D + n0 + kq * 4);
        }
        __syncthreads();
        #pragma unroll 8
        for (int k = 0; k < 64; k++) {
            float4 b = *(const float4*)&Bs[k][tx * 4];
            float a0 = As[ty * 4 + 0][k];
            float a1 = As[ty * 4 + 1][k];
            float a2 = As[ty * 4 + 2][k];
            float a3 = As[ty * 4 + 3][k];
            acc[0][0] = fmaf(a0, b.x, acc[0][0]); acc[0][1] = fmaf(a0, b.y, acc[0][1]);
            acc[0][2] = fmaf(a0, b.z, acc[0][2]); acc[0][3] = fmaf(a0, b.w, acc[0][3]);
            acc[1][0] = fmaf(a1, b.x, acc[1][0]); acc[1][1] = fmaf(a1, b.y, acc[1][1]);
            acc[1][2] = fmaf(a1, b.z, acc[1][2]); acc[1][3] = fmaf(a1, b.w, acc[1][3]);
            acc[2][0] = fmaf(a2, b.x, acc[2][0]); acc[2][1] = fmaf(a2, b.y, acc[2][1]);
            acc[2][2] = fmaf(a2, b.z, acc[2][2]); acc[2][3] = fmaf(a2, b.w, acc[2][3]);
            acc[3][0] = fmaf(a3, b.x, acc[3][0]); acc[3][1] = fmaf(a3, b.y, acc[3][1]);
            acc[3][2] = fmaf(a3, b.z, acc[3][2]); acc[3][3] = fmaf(a3, b.w, acc[3][3]);
        }
        __syncthreads();
    }
    #pragma unroll
    for (int i = 0; i < 4; i++) {
        int gm = m0 + ty * 4 + i;
        if (gm < M)
            *(float4*)(C + (size_t)gm * D + n0 + tx * 4) =
                make_float4(acc[i][0], acc[i][1], acc[i][2], acc[i][3]);
    }
}

// ---------------- Final GEMM: out = A @ W + bias  (A: Mx128, W: 128x64) ----------------

__global__ __launch_bounds__(256)
void gemm_out(const float* __restrict__ A, int M, const float* __restrict__ W,
              const float* __restrict__ bias, float* __restrict__ Cout) {
    __shared__ float As[64][68];
    __shared__ float Bs[64][68];
    int tid = threadIdx.x;
    int tx = tid & 15, ty = tid >> 4;
    int m0 = blockIdx.x * 64;

    float acc[4][4] = {{0.f}};
    int r = tid >> 4;
    int kq = tid & 15;

    for (int kt = 0; kt < D; kt += 64) {
        #pragma unroll
        for (int i = 0; i < 4; i++) {
            int row = r + i * 16;
            int gm = m0 + row;
            float4 v = make_float4(0.f, 0.f, 0.f, 0.f);
            if (gm < M) v = *(const float4*)(A + (size_t)gm * D + kt + kq * 4);
            *(float4*)&As[row][kq * 4] = v;
        }
        #pragma unroll
        for (int i = 0; i < 4; i++) {
            int k = r + i * 16;
            *(float4*)&Bs[k][kq * 4] = *(const float4*)(W + (size_t)(kt + k) * OUTD + kq * 4);
        }
        __syncthreads();
        #pragma unroll 8
        for (int k = 0; k < 64; k++) {
            float4 b = *(const float4*)&Bs[k][tx * 4];
            float a0 = As[ty * 4 + 0][k];
            float a1 = As[ty * 4 + 1][k];
            float a2 = As[ty * 4 + 2][k];
            float a3 = As[ty * 4 + 3][k];
            acc[0][0] = fmaf(a0, b.x, acc[0][0]); acc[0][1] = fmaf(a0, b.y, acc[0][1]);
            acc[0][2] = fmaf(a0, b.z, acc[0][2]); acc[0][3] = fmaf(a0, b.w, acc[0][3]);
            acc[1][0] = fmaf(a1, b.x, acc[1][0]); acc[1][1] = fmaf(a1, b.y, acc[1][1]);
            acc[1][2] = fmaf(a1, b.z, acc[1][2]); acc[1][3] = fmaf(a1, b.w, acc[1][3]);
            acc[2][0] = fmaf(a2, b.x, acc[2][0]); acc[2][1] = fmaf(a2, b.y, acc[2][1]);
            acc[2][2] = fmaf(a2, b.z, acc[2][2]); acc[2][3] = fmaf(a2, b.w, acc[2][3]);
            acc[3][0] = fmaf(a3, b.x, acc[3][0]); acc[3][1] = fmaf(a3, b.y, acc[3][1]);
            acc[3][2] = fmaf(a3, b.z, acc[3][2]); acc[3][3] = fmaf(a3, b.w, acc[3][3]);
        }
        __syncthreads();
    }
    float4 bv = *(const float4*)(bias + tx * 4);
    #pragma unroll
    for (int i = 0; i < 4; i++) {
        int gm = m0 + ty * 4 + i;
        if (gm < M)
            *(float4*)(Cout + (size_t)gm * OUTD + tx * 4) =
                make_float4(acc[i][0] + bv.x, acc[i][1] + bv.y, acc[i][2] + bv.z, acc[i][3] + bv.w);
    }
}

// ---------------- Fused aggregation + bias + relu + JK-max ----------------
// h_out[n] = relu(t_self[n] + bcomb + (1-a)/deg_in * sum_{e:dst=n} t_std[src_e]
//                                  + a/deg_out   * sum_{e:src=n} t_dts[dst_e])
// jk = first ? h_out : max(jk, h_out)

__global__ __launch_bounds__(256)
void agg_epilogue(const float* __restrict__ t_self, const float* __restrict__ t_std,
                  const float* __restrict__ t_dts,
                  const float* __restrict__ bself, const float* __restrict__ bstd,
                  const float* __restrict__ bdts,
                  const int* __restrict__ row_in, const int* __restrict__ col_in,
                  const int* __restrict__ row_out, const int* __restrict__ col_out,
                  const float* __restrict__ alpha_p,
                  float* __restrict__ h_out, float* __restrict__ jk, int first, int N) {
    int wv = threadIdx.x >> 6;
    int lane = threadIdx.x & 63;
    int n = blockIdx.x * 4 + wv;
    if (n >= N) return;
    float a = alpha_p[0];
    int s_in = row_in[n], e_in = row_in[n + 1];
    int s_out = row_out[n], e_out = row_out[n + 1];

    float2 ain = make_float2(0.f, 0.f);
    float2 aout = make_float2(0.f, 0.f);
    for (int e = s_in; e < e_in; e++) {
        int u = col_in[e];
        float2 v = *(const float2*)(t_std + (size_t)u * D + lane * 2);
        ain.x += v.x; ain.y += v.y;
    }
    for (int e = s_out; e < e_out; e++) {
        int u = col_out[e];
        float2 v = *(const float2*)(t_dts + (size_t)u * D + lane * 2);
        aout.x += v.x; aout.y += v.y;
    }
    float win = (1.0f - a) / (float)max(e_in - s_in, 1);
    float wout = a / (float)max(e_out - s_out, 1);
    int j = lane * 2;
    float2 ts = *(const float2*)(t_self + (size_t)n * D + j);
    float bx = bself[j] + (1.0f - a) * bstd[j] + a * bdts[j];
    float by = bself[j + 1] + (1.0f - a) * bstd[j + 1] + a * bdts[j + 1];
    float hx = fmaxf(ts.x + bx + win * ain.x + wout * aout.x, 0.f);
    float hy = fmaxf(ts.y + by + win * ain.y + wout * aout.y, 0.f);
    *(float2*)(h_out + (size_t)n * D + j) = make_float2(hx, hy);
    float2* jp = (float2*)(jk + (size_t)n * D + j);
    if (first) {
        *jp = make_float2(hx, hy);
    } else {
        float2 old = *jp;
        *jp = make_float2(fmaxf(old.x, hx), fmaxf(old.y, hy));
    }
}

// ---------------- launch ----------------

extern "C" void kernel_launch(void* const* d_in, const int* in_sizes, int n_in,
                              void* d_out, int out_size, void* d_ws, size_t ws_size,
                              hipStream_t stream) {
    const float* x     = (const float*)d_in[0];
    const int*   ei    = (const int*)d_in[1];
    const float* Wself = (const float*)d_in[2];
    const float* bself = (const float*)d_in[3];
    const float* Wstd  = (const float*)d_in[4];
    const float* bstd  = (const float*)d_in[5];
    const float* Wdts  = (const float*)d_in[6];
    const float* bdts  = (const float*)d_in[7];
    const float* Wlin  = (const float*)d_in[8];
    const float* blin  = (const float*)d_in[9];
    const float* alpha = (const float*)d_in[10];

    int N = in_sizes[0] / D;   // 50000
    int E = in_sizes[1] / 2;   // 800000

    char* p = (char*)d_ws;
    auto alloc = [&](size_t bytes) {
        char* q = p;
        p += (bytes + 255) & ~(size_t)255;
        return q;
    };
    int* cnt_in  = (int*)alloc((size_t)N * 4);
    int* cnt_out = (int*)alloc((size_t)N * 4);
    int* row_in  = (int*)alloc((size_t)(N + 1) * 4);
    int* row_out = (int*)alloc((size_t)(N + 1) * 4);
    int* col_in  = (int*)alloc((size_t)E * 4);
    int* col_out = (int*)alloc((size_t)E * 4);
    float* t1 = (float*)alloc((size_t)N * D * 4);
    float* t2 = (float*)alloc((size_t)N * D * 4);
    float* t3 = (float*)alloc((size_t)N * D * 4);
    float* hA = (float*)alloc((size_t)N * D * 4);
    float* hB = (float*)alloc((size_t)N * D * 4);
    float* jk = (float*)alloc((size_t)N * D * 4);

    const int* srcp = ei;
    const int* dstp = ei + E;

    hipMemsetAsync(cnt_in, 0, (size_t)N * 4, stream);
    hipMemsetAsync(cnt_out, 0, (size_t)N * 4, stream);
    count_deg<<<ceil_div(E, 256), 256, 0, stream>>>(srcp, dstp, E, cnt_out, cnt_in);
    scan2<<<2, 1024, 0, stream>>>(cnt_in, row_in, cnt_out, row_out, N);
    hipMemsetAsync(cnt_in, 0, (size_t)N * 4, stream);
    hipMemsetAsync(cnt_out, 0, (size_t)N * 4, stream);
    fill_csr<<<ceil_div(E, 256), 256, 0, stream>>>(srcp, dstp, E, row_in, row_out,
                                                   cnt_in, cnt_out, col_in, col_out);

    const float* h = x;
    float* hbufs[2] = {hA, hB};
    int gm = ceil_div(N, 64);
    for (int l = 0; l < LAYERS; l++) {
        gemm3<<<dim3(gm, 2, 3), 256, 0, stream>>>(h, N,
            Wself + (size_t)l * D * D, Wstd + (size_t)l * D * D, Wdts + (size_t)l * D * D,
            t1, t2, t3);
        float* hn = hbufs[l & 1];
        agg_epilogue<<<ceil_div(N, 4), 256, 0, stream>>>(t1, t2, t3,
            bself + (size_t)l * D, bstd + (size_t)l * D, bdts + (size_t)l * D,
            row_in, col_in, row_out, col_out, alpha, hn, jk, (l == 0) ? 1 : 0, N);
        h = hn;
    }
    gemm_out<<<dim3(gm, 1, 1), 256, 0, stream>>>(jk, N, Wlin, blin, (float*)d_out);
}

// Round 2
// 845.407 us; speedup vs baseline: 1.1854x; 1.1854x over previous
//
#include <hip/hip_runtime.h>

#define D 128
#define OUTD 64
#define LAYERS 3

typedef __attribute__((ext_vector_type(8))) short short8;
typedef __attribute__((ext_vector_type(4))) float float4v;

static inline int ceil_div(int a, int b) { return (a + b - 1) / b; }

__device__ __forceinline__ unsigned short f2bf(float f) {
    unsigned int u = __float_as_uint(f);
    unsigned int r = u + 0x7FFFu + ((u >> 16) & 1u);
    return (unsigned short)(r >> 16);
}

// ---------------- CSR build ----------------

__global__ __launch_bounds__(256)
void count_deg(const int* __restrict__ src, const int* __restrict__ dst, int E,
               int* cnt_out, int* cnt_in) {
    int e = blockIdx.x * 256 + threadIdx.x;
    if (e < E) {
        atomicAdd(&cnt_out[src[e]], 1);
        atomicAdd(&cnt_in[dst[e]], 1);
    }
}

__global__ __launch_bounds__(1024)
void scan2(const int* __restrict__ cnt_a, int* __restrict__ row_a,
           const int* __restrict__ cnt_b, int* __restrict__ row_b, int n) {
    const int* cnt = blockIdx.x ? cnt_b : cnt_a;
    int* row = blockIdx.x ? row_b : row_a;
    __shared__ int wsum[16];
    __shared__ int chunk_total;
    int lane = threadIdx.x & 63;
    int w = threadIdx.x >> 6;
    int carry = 0;
    for (int base = 0; base < n; base += 1024) {
        int i = base + threadIdx.x;
        int v = (i < n) ? cnt[i] : 0;
        int x = v;
        #pragma unroll
        for (int off = 1; off < 64; off <<= 1) {
            int y = __shfl_up(x, off, 64);
            if (lane >= off) x += y;
        }
        if (lane == 63) wsum[w] = x;
        __syncthreads();
        if (w == 0 && lane < 16) {
            int s = wsum[lane];
            #pragma unroll
            for (int off = 1; off < 16; off <<= 1) {
                int y = __shfl_up(s, off, 16);
                if (lane >= off) s += y;
            }
            wsum[lane] = s;
            if (lane == 15) chunk_total = s;
        }
        __syncthreads();
        int wpre = (w == 0) ? 0 : wsum[w - 1];
        if (i < n) row[i] = carry + wpre + (x - v);
        carry += chunk_total;
        __syncthreads();
    }
    if (threadIdx.x == 0) row[n] = carry;
}

__global__ __launch_bounds__(256)
void fill_csr(const int* __restrict__ src, const int* __restrict__ dst, int E,
              const int* __restrict__ row_in, const int* __restrict__ row_out,
              int* cur_in, int* cur_out,
              int* __restrict__ col_in, int* __restrict__ col_out) {
    int e = blockIdx.x * 256 + threadIdx.x;
    if (e < E) {
        int s = src[e], d = dst[e];
        int p = atomicAdd(&cur_in[d], 1);
        col_in[row_in[d] + p] = s;
        int q = atomicAdd(&cur_out[s], 1);
        col_out[row_out[s] + q] = d;
    }
}

// ---------------- converts ----------------

__global__ __launch_bounds__(256)
void convert_x(const float* __restrict__ x, unsigned long long* __restrict__ xb, int n4) {
    int i = blockIdx.x * 256 + threadIdx.x;
    if (i < n4) {
        float4 v = ((const float4*)x)[i];
        unsigned long long p =
            (unsigned long long)f2bf(v.x) |
            ((unsigned long long)f2bf(v.y) << 16) |
            ((unsigned long long)f2bf(v.z) << 32) |
            ((unsigned long long)f2bf(v.w) << 48);
        xb[i] = p;
    }
}

// transpose + convert the 9 per-layer weight matrices to bf16: wt[b][n][k] = W[b][k][n]
__global__ __launch_bounds__(256)
void convert_wt(const float* __restrict__ Wself, const float* __restrict__ Wstd,
                const float* __restrict__ Wdts, short* __restrict__ wt) {
    int b = blockIdx.x;            // 0..8
    int l = b / 3, m = b % 3;
    const float* W = (m == 0 ? Wself : (m == 1 ? Wstd : Wdts)) + (size_t)l * D * D;
    short* o = wt + (size_t)b * D * D;
    for (int idx = threadIdx.x; idx < D * D; idx += 256) {
        int k = idx >> 7, n = idx & 127;
        o[n * D + k] = (short)f2bf(W[idx]);
    }
}

// ---------------- bf16 MFMA GEMM: t1(fp32), t2b/t3b(bf16) = A @ {Wself,Wstd,Wdts} ----------------
// A: M x 128 bf16 row-major. Wt: per-matrix 128x128 bf16, TRANSPOSED (wt[n][k]).
// Block: 256 threads = 4 waves, 128(M)x128(N) tile, full K=128 in LDS.

__global__ __launch_bounds__(256)
void gemm3_bf16(const short* __restrict__ Abf, int M,
                const short* __restrict__ wt3,   // 3 transposed bf16 matrices
                float* __restrict__ t1, short* __restrict__ t2b, short* __restrict__ t3b) {
    __shared__ __align__(16) short As[128][136];
    __shared__ __align__(16) short Bs[128][136];
    int tid = threadIdx.x;
    int m0 = blockIdx.x * 128;
    int z = blockIdx.z;
    const short* Bt = wt3 + (size_t)z * D * D;

    // stage A tile (bf16 global -> LDS, padded rows)
    #pragma unroll
    for (int i = 0; i < 8; i++) {
        int v = tid + i * 256;         // 0..2047
        int row = v >> 4;
        int c8 = v & 15;
        int gr = m0 + row;
        short8 val = {0, 0, 0, 0, 0, 0, 0, 0};
        if (gr < M) val = *(const short8*)(Abf + (size_t)gr * D + c8 * 8);
        *(short8*)&As[row][c8 * 8] = val;
    }
    // stage B (already transposed: Bs[n][k])
    #pragma unroll
    for (int i = 0; i < 8; i++) {
        int v = tid + i * 256;
        int row = v >> 4;
        int c8 = v & 15;
        *(short8*)&Bs[row][c8 * 8] = *(const short8*)(Bt + (size_t)row * D + c8 * 8);
    }
    __syncthreads();

    int wave = tid >> 6, lane = tid & 63;
    int quad = lane >> 4, r16 = lane & 15;
    int mrow = wave * 32;

    float4v acc[2][8];
    #pragma unroll
    for (int a = 0; a < 2; a++)
        #pragma unroll
        for (int b = 0; b < 8; b++)
            acc[a][b] = (float4v){0.f, 0.f, 0.f, 0.f};

    #pragma unroll
    for (int kc = 0; kc < 4; kc++) {
        short8 a0 = *(const short8*)&As[mrow + r16][kc * 32 + quad * 8];
        short8 a1 = *(const short8*)&As[mrow + 16 + r16][kc * 32 + quad * 8];
        #pragma unroll
        for (int nt = 0; nt < 8; nt++) {
            short8 b = *(const short8*)&Bs[nt * 16 + r16][kc * 32 + quad * 8];
            acc[0][nt] = __builtin_amdgcn_mfma_f32_16x16x32_bf16(a0, b, acc[0][nt], 0, 0, 0);
            acc[1][nt] = __builtin_amdgcn_mfma_f32_16x16x32_bf16(a1, b, acc[1][nt], 0, 0, 0);
        }
    }

    // C/D layout: col = lane&15, row = quad*4 + reg
    if (z == 0) {
        #pragma unroll
        for (int rt = 0; rt < 2; rt++)
            #pragma unroll
            for (int nt = 0; nt < 8; nt++)
                #pragma unroll
                for (int reg = 0; reg < 4; reg++) {
                    int row = m0 + mrow + rt * 16 + quad * 4 + reg;
                    if (row < M) t1[(size_t)row * D + nt * 16 + r16] = acc[rt][nt][reg];
                }
    } else {
        short* Cb = (z == 1) ? t2b : t3b;
        #pragma unroll
        for (int rt = 0; rt < 2; rt++)
            #pragma unroll
            for (int nt = 0; nt < 8; nt++)
                #pragma unroll
                for (int reg = 0; reg < 4; reg++) {
                    int row = m0 + mrow + rt * 16 + quad * 4 + reg;
                    if (row < M) Cb[(size_t)row * D + nt * 16 + r16] = (short)f2bf(acc[rt][nt][reg]);
                }
    }
}

// ---------------- Final GEMM: out = jk @ Wlin + blin (fp32 SIMT) ----------------

__global__ __launch_bounds__(256)
void gemm_out(const float* __restrict__ A, int M, const float* __restrict__ W,
              const float* __restrict__ bias, float* __restrict__ Cout) {
    __shared__ float As[64][68];
    __shared__ float Bs[64][68];
    int tid = threadIdx.x;
    int tx = tid & 15, ty = tid >> 4;
    int m0 = blockIdx.x * 64;

    float acc[4][4] = {{0.f}};
    int r = tid >> 4;
    int kq = tid & 15;

    for (int kt = 0; kt < D; kt += 64) {
        #pragma unroll
        for (int i = 0; i < 4; i++) {
            int row = r + i * 16;
            int gm = m0 + row;
            float4 v = make_float4(0.f, 0.f, 0.f, 0.f);
            if (gm < M) v = *(const float4*)(A + (size_t)gm * D + kt + kq * 4);
            *(float4*)&As[row][kq * 4] = v;
        }
        #pragma unroll
        for (int i = 0; i < 4; i++) {
            int k = r + i * 16;
            *(float4*)&Bs[k][kq * 4] = *(const float4*)(W + (size_t)(kt + k) * OUTD + kq * 4);
        }
        __syncthreads();
        #pragma unroll 8
        for (int k = 0; k < 64; k++) {
            float4 b = *(const float4*)&Bs[k][tx * 4];
            float a0 = As[ty * 4 + 0][k];
            float a1 = As[ty * 4 + 1][k];
            float a2 = As[ty * 4 + 2][k];
            float a3 = As[ty * 4 + 3][k];
            acc[0][0] = fmaf(a0, b.x, acc[0][0]); acc[0][1] = fmaf(a0, b.y, acc[0][1]);
            acc[0][2] = fmaf(a0, b.z, acc[0][2]); acc[0][3] = fmaf(a0, b.w, acc[0][3]);
            acc[1][0] = fmaf(a1, b.x, acc[1][0]); acc[1][1] = fmaf(a1, b.y, acc[1][1]);
            acc[1][2] = fmaf(a1, b.z, acc[1][2]); acc[1][3] = fmaf(a1, b.w, acc[1][3]);
            acc[2][0] = fmaf(a2, b.x, acc[2][0]); acc[2][1] = fmaf(a2, b.y, acc[2][1]);
            acc[2][2] = fmaf(a2, b.z, acc[2][2]); acc[2][3] = fmaf(a2, b.w, acc[2][3]);
            acc[3][0] = fmaf(a3, b.x, acc[3][0]); acc[3][1] = fmaf(a3, b.y, acc[3][1]);
            acc[3][2] = fmaf(a3, b.z, acc[3][2]); acc[3][3] = fmaf(a3, b.w, acc[3][3]);
        }
        __syncthreads();
    }
    float4 bv = *(const float4*)(bias + tx * 4);
    #pragma unroll
    for (int i = 0; i < 4; i++) {
        int gm = m0 + ty * 4 + i;
        if (gm < M)
            *(float4*)(Cout + (size_t)gm * OUTD + tx * 4) =
                make_float4(acc[i][0] + bv.x, acc[i][1] + bv.y, acc[i][2] + bv.z, acc[i][3] + bv.w);
    }
}

// ---------------- Fused aggregation + bias + relu + JK-max (bf16 gathers) ----------------
// t_std2/t_dts2: bf16 rows viewed as uint (2 bf16 per uint, 64 uints per row)

__global__ __launch_bounds__(256)
void agg_epilogue(const float* __restrict__ t_self,
                  const unsigned int* __restrict__ t_std2,
                  const unsigned int* __restrict__ t_dts2,
                  const float* __restrict__ bself, const float* __restrict__ bstd,
                  const float* __restrict__ bdts,
                  const int* __restrict__ row_in, const int* __restrict__ col_in,
                  const int* __restrict__ row_out, const int* __restrict__ col_out,
                  const float* __restrict__ alpha_p,
                  unsigned int* __restrict__ h_out, float* __restrict__ jk,
                  int first, int N) {
    int wv = threadIdx.x >> 6;
    int lane = threadIdx.x & 63;
    int n = blockIdx.x * 4 + wv;
    if (n >= N) return;
    float a = alpha_p[0];
    int s_in = row_in[n], e_in = row_in[n + 1];
    int s_out = row_out[n], e_out = row_out[n + 1];

    float ax = 0.f, ay = 0.f, ox = 0.f, oy = 0.f;
    for (int e = s_in; e < e_in; e++) {
        int u = col_in[e];
        unsigned int v = t_std2[(size_t)u * 64 + lane];
        ax += __uint_as_float(v << 16);
        ay += __uint_as_float(v & 0xFFFF0000u);
    }
    for (int e = s_out; e < e_out; e++) {
        int u = col_out[e];
        unsigned int v = t_dts2[(size_t)u * 64 + lane];
        ox += __uint_as_float(v << 16);
        oy += __uint_as_float(v & 0xFFFF0000u);
    }
    float win = (1.0f - a) / (float)max(e_in - s_in, 1);
    float wout = a / (float)max(e_out - s_out, 1);
    int j = lane * 2;
    float2 ts = *(const float2*)(t_self + (size_t)n * D + j);
    float bx = bself[j] + (1.0f - a) * bstd[j] + a * bdts[j];
    float by = bself[j + 1] + (1.0f - a) * bstd[j + 1] + a * bdts[j + 1];
    float hx = fmaxf(ts.x + bx + win * ax + wout * ox, 0.f);
    float hy = fmaxf(ts.y + by + win * ay + wout * oy, 0.f);
    // h for next layer's GEMM input: bf16 packed
    h_out[(size_t)n * 64 + lane] = (unsigned int)f2bf(hx) | ((unsigned int)f2bf(hy) << 16);
    // JK max in fp32
    float2* jp = (float2*)(jk + (size_t)n * D + j);
    if (first) {
        *jp = make_float2(hx, hy);
    } else {
        float2 old = *jp;
        *jp = make_float2(fmaxf(old.x, hx), fmaxf(old.y, hy));
    }
}

// ---------------- launch ----------------

extern "C" void kernel_launch(void* const* d_in, const int* in_sizes, int n_in,
                              void* d_out, int out_size, void* d_ws, size_t ws_size,
                              hipStream_t stream) {
    const float* x     = (const float*)d_in[0];
    const int*   ei    = (const int*)d_in[1];
    const float* Wself = (const float*)d_in[2];
    const float* bself = (const float*)d_in[3];
    const float* Wstd  = (const float*)d_in[4];
    const float* bstd  = (const float*)d_in[5];
    const float* Wdts  = (const float*)d_in[6];
    const float* bdts  = (const float*)d_in[7];
    const float* Wlin  = (const float*)d_in[8];
    const float* blin  = (const float*)d_in[9];
    const float* alpha = (const float*)d_in[10];

    int N = in_sizes[0] / D;   // 50000
    int E = in_sizes[1] / 2;   // 800000

    char* p = (char*)d_ws;
    auto alloc = [&](size_t bytes) {
        char* q = p;
        p += (bytes + 255) & ~(size_t)255;
        return q;
    };
    int* cnt_in  = (int*)alloc((size_t)N * 4);
    int* cnt_out = (int*)alloc((size_t)N * 4);
    int* row_in  = (int*)alloc((size_t)(N + 1) * 4);
    int* row_out = (int*)alloc((size_t)(N + 1) * 4);
    int* col_in  = (int*)alloc((size_t)E * 4);
    int* col_out = (int*)alloc((size_t)E * 4);
    short* xb  = (short*)alloc((size_t)N * D * 2);       // x in bf16
    short* hb  = (short*)alloc((size_t)N * D * 2);       // h in bf16
    short* wt  = (short*)alloc((size_t)9 * D * D * 2);   // transposed bf16 weights
    float* t1  = (float*)alloc((size_t)N * D * 4);       // self-transform, fp32
    short* t2b = (short*)alloc((size_t)N * D * 2);       // std-transform, bf16
    short* t3b = (short*)alloc((size_t)N * D * 2);       // dts-transform, bf16
    float* jk  = (float*)alloc((size_t)N * D * 4);       // JK max, fp32

    const int* srcp = ei;
    const int* dstp = ei + E;

    hipMemsetAsync(cnt_in, 0, (size_t)N * 4, stream);
    hipMemsetAsync(cnt_out, 0, (size_t)N * 4, stream);
    count_deg<<<ceil_div(E, 256), 256, 0, stream>>>(srcp, dstp, E, cnt_out, cnt_in);
    scan2<<<2, 1024, 0, stream>>>(cnt_in, row_in, cnt_out, row_out, N);
    hipMemsetAsync(cnt_in, 0, (size_t)N * 4, stream);
    hipMemsetAsync(cnt_out, 0, (size_t)N * 4, stream);
    fill_csr<<<ceil_div(E, 256), 256, 0, stream>>>(srcp, dstp, E, row_in, row_out,
                                                   cnt_in, cnt_out, col_in, col_out);

    convert_x<<<ceil_div(N * D / 4, 256), 256, 0, stream>>>(x, (unsigned long long*)xb, N * D / 4);
    convert_wt<<<9, 256, 0, stream>>>(Wself, Wstd, Wdts, wt);

    const short* hin = xb;
    int gm = ceil_div(N, 128);
    for (int l = 0; l < LAYERS; l++) {
        gemm3_bf16<<<dim3(gm, 1, 3), 256, 0, stream>>>(hin, N, wt + (size_t)l * 3 * D * D,
                                                       t1, t2b, t3b);
        agg_epilogue<<<ceil_div(N, 4), 256, 0, stream>>>(t1,
            (const unsigned int*)t2b, (const unsigned int*)t3b,
            bself + (size_t)l * D, bstd + (size_t)l * D, bdts + (size_t)l * D,
            row_in, col_in, row_out, col_out, alpha,
            (unsigned int*)hb, jk, (l == 0) ? 1 : 0, N);
        hin = hb;
    }
    gemm_out<<<ceil_div(N, 64), 256, 0, stream>>>(jk, N, Wlin, blin, (float*)d_out);
}

// Round 3
// 577.892 us; speedup vs baseline: 1.7341x; 1.4629x over previous
//
#include <hip/hip_runtime.h>

#define D 128
#define OUTD 64
#define LAYERS 3

typedef __attribute__((ext_vector_type(8))) short short8;
typedef __attribute__((ext_vector_type(4))) float float4v;

static inline int ceil_div(int a, int b) { return (a + b - 1) / b; }

__device__ __forceinline__ unsigned short f2bf(float f) {
    unsigned int u = __float_as_uint(f);
    unsigned int r = u + 0x7FFFu + ((u >> 16) & 1u);
    return (unsigned short)(r >> 16);
}

// ---------------- CSR build ----------------

__global__ __launch_bounds__(256)
void count_deg(const int* __restrict__ src, const int* __restrict__ dst, int E,
               int* cnt_out, int* cnt_in) {
    int e = blockIdx.x * 256 + threadIdx.x;
    if (e < E) {
        atomicAdd(&cnt_out[src[e]], 1);
        atomicAdd(&cnt_in[dst[e]], 1);
    }
}

__global__ __launch_bounds__(1024)
void scan2(const int* __restrict__ cnt_a, int* __restrict__ row_a,
           const int* __restrict__ cnt_b, int* __restrict__ row_b, int n) {
    const int* cnt = blockIdx.x ? cnt_b : cnt_a;
    int* row = blockIdx.x ? row_b : row_a;
    __shared__ int wsum[16];
    __shared__ int chunk_total;
    int lane = threadIdx.x & 63;
    int w = threadIdx.x >> 6;
    int carry = 0;
    for (int base = 0; base < n; base += 1024) {
        int i = base + threadIdx.x;
        int v = (i < n) ? cnt[i] : 0;
        int x = v;
        #pragma unroll
        for (int off = 1; off < 64; off <<= 1) {
            int y = __shfl_up(x, off, 64);
            if (lane >= off) x += y;
        }
        if (lane == 63) wsum[w] = x;
        __syncthreads();
        if (w == 0 && lane < 16) {
            int s = wsum[lane];
            #pragma unroll
            for (int off = 1; off < 16; off <<= 1) {
                int y = __shfl_up(s, off, 16);
                if (lane >= off) s += y;
            }
            wsum[lane] = s;
            if (lane == 15) chunk_total = s;
        }
        __syncthreads();
        int wpre = (w == 0) ? 0 : wsum[w - 1];
        if (i < n) row[i] = carry + wpre + (x - v);
        carry += chunk_total;
        __syncthreads();
    }
    if (threadIdx.x == 0) row[n] = carry;
}

__global__ __launch_bounds__(256)
void fill_csr(const int* __restrict__ src, const int* __restrict__ dst, int E,
              const int* __restrict__ row_in, const int* __restrict__ row_out,
              int* cur_in, int* cur_out,
              int* __restrict__ col_in, int* __restrict__ col_out) {
    int e = blockIdx.x * 256 + threadIdx.x;
    if (e < E) {
        int s = src[e], d = dst[e];
        int p = atomicAdd(&cur_in[d], 1);
        col_in[row_in[d] + p] = s;
        int q = atomicAdd(&cur_out[s], 1);
        col_out[row_out[s] + q] = d;
    }
}

// ---------------- converts ----------------

__global__ __launch_bounds__(256)
void convert_x(const float* __restrict__ x, unsigned long long* __restrict__ xb, int n4) {
    int i = blockIdx.x * 256 + threadIdx.x;
    if (i < n4) {
        float4 v = ((const float4*)x)[i];
        unsigned long long p =
            (unsigned long long)f2bf(v.x) |
            ((unsigned long long)f2bf(v.y) << 16) |
            ((unsigned long long)f2bf(v.z) << 32) |
            ((unsigned long long)f2bf(v.w) << 48);
        xb[i] = p;
    }
}

// transpose + convert the 9 per-layer weight matrices to bf16: wt[b][n][k] = W[b][k][n]
__global__ __launch_bounds__(256)
void convert_wt(const float* __restrict__ Wself, const float* __restrict__ Wstd,
                const float* __restrict__ Wdts, short* __restrict__ wt) {
    int b = blockIdx.x;            // 0..8
    int l = b / 3, m = b % 3;
    const float* W = (m == 0 ? Wself : (m == 1 ? Wstd : Wdts)) + (size_t)l * D * D;
    short* o = wt + (size_t)b * D * D;
    for (int idx = threadIdx.x; idx < D * D; idx += 256) {
        int k = idx >> 7, n = idx & 127;
        o[n * D + k] = (short)f2bf(W[idx]);
    }
}

// ---------------- bf16 MFMA GEMM ----------------

__global__ __launch_bounds__(256)
void gemm3_bf16(const short* __restrict__ Abf, int M,
                const short* __restrict__ wt3,
                float* __restrict__ t1, short* __restrict__ t2b, short* __restrict__ t3b) {
    __shared__ __align__(16) short As[128][136];
    __shared__ __align__(16) short Bs[128][136];
    int tid = threadIdx.x;
    int m0 = blockIdx.x * 128;
    int z = blockIdx.z;
    const short* Bt = wt3 + (size_t)z * D * D;

    #pragma unroll
    for (int i = 0; i < 8; i++) {
        int v = tid + i * 256;
        int row = v >> 4;
        int c8 = v & 15;
        int gr = m0 + row;
        short8 val = {0, 0, 0, 0, 0, 0, 0, 0};
        if (gr < M) val = *(const short8*)(Abf + (size_t)gr * D + c8 * 8);
        *(short8*)&As[row][c8 * 8] = val;
    }
    #pragma unroll
    for (int i = 0; i < 8; i++) {
        int v = tid + i * 256;
        int row = v >> 4;
        int c8 = v & 15;
        *(short8*)&Bs[row][c8 * 8] = *(const short8*)(Bt + (size_t)row * D + c8 * 8);
    }
    __syncthreads();

    int wave = tid >> 6, lane = tid & 63;
    int quad = lane >> 4, r16 = lane & 15;
    int mrow = wave * 32;

    float4v acc[2][8];
    #pragma unroll
    for (int a = 0; a < 2; a++)
        #pragma unroll
        for (int b = 0; b < 8; b++)
            acc[a][b] = (float4v){0.f, 0.f, 0.f, 0.f};

    #pragma unroll
    for (int kc = 0; kc < 4; kc++) {
        short8 a0 = *(const short8*)&As[mrow + r16][kc * 32 + quad * 8];
        short8 a1 = *(const short8*)&As[mrow + 16 + r16][kc * 32 + quad * 8];
        #pragma unroll
        for (int nt = 0; nt < 8; nt++) {
            short8 b = *(const short8*)&Bs[nt * 16 + r16][kc * 32 + quad * 8];
            acc[0][nt] = __builtin_amdgcn_mfma_f32_16x16x32_bf16(a0, b, acc[0][nt], 0, 0, 0);
            acc[1][nt] = __builtin_amdgcn_mfma_f32_16x16x32_bf16(a1, b, acc[1][nt], 0, 0, 0);
        }
    }

    if (z == 0) {
        #pragma unroll
        for (int rt = 0; rt < 2; rt++)
            #pragma unroll
            for (int nt = 0; nt < 8; nt++)
                #pragma unroll
                for (int reg = 0; reg < 4; reg++) {
                    int row = m0 + mrow + rt * 16 + quad * 4 + reg;
                    if (row < M) t1[(size_t)row * D + nt * 16 + r16] = acc[rt][nt][reg];
                }
    } else {
        short* Cb = (z == 1) ? t2b : t3b;
        #pragma unroll
        for (int rt = 0; rt < 2; rt++)
            #pragma unroll
            for (int nt = 0; nt < 8; nt++)
                #pragma unroll
                for (int reg = 0; reg < 4; reg++) {
                    int row = m0 + mrow + rt * 16 + quad * 4 + reg;
                    if (row < M) Cb[(size_t)row * D + nt * 16 + r16] = (short)f2bf(acc[rt][nt][reg]);
                }
    }
}

// ---------------- Final GEMM: out = jk @ Wlin + blin (fp32 SIMT) ----------------

__global__ __launch_bounds__(256)
void gemm_out(const float* __restrict__ A, int M, const float* __restrict__ W,
              const float* __restrict__ bias, float* __restrict__ Cout) {
    __shared__ float As[64][68];
    __shared__ float Bs[64][68];
    int tid = threadIdx.x;
    int tx = tid & 15, ty = tid >> 4;
    int m0 = blockIdx.x * 64;

    float acc[4][4] = {{0.f}};
    int r = tid >> 4;
    int kq = tid & 15;

    for (int kt = 0; kt < D; kt += 64) {
        #pragma unroll
        for (int i = 0; i < 4; i++) {
            int row = r + i * 16;
            int gm = m0 + row;
            float4 v = make_float4(0.f, 0.f, 0.f, 0.f);
            if (gm < M) v = *(const float4*)(A + (size_t)gm * D + kt + kq * 4);
            *(float4*)&As[row][kq * 4] = v;
        }
        #pragma unroll
        for (int i = 0; i < 4; i++) {
            int k = r + i * 16;
            *(float4*)&Bs[k][kq * 4] = *(const float4*)(W + (size_t)(kt + k) * OUTD + kq * 4);
        }
        __syncthreads();
        #pragma unroll 8
        for (int k = 0; k < 64; k++) {
            float4 b = *(const float4*)&Bs[k][tx * 4];
            float a0 = As[ty * 4 + 0][k];
            float a1 = As[ty * 4 + 1][k];
            float a2 = As[ty * 4 + 2][k];
            float a3 = As[ty * 4 + 3][k];
            acc[0][0] = fmaf(a0, b.x, acc[0][0]); acc[0][1] = fmaf(a0, b.y, acc[0][1]);
            acc[0][2] = fmaf(a0, b.z, acc[0][2]); acc[0][3] = fmaf(a0, b.w, acc[0][3]);
            acc[1][0] = fmaf(a1, b.x, acc[1][0]); acc[1][1] = fmaf(a1, b.y, acc[1][1]);
            acc[1][2] = fmaf(a1, b.z, acc[1][2]); acc[1][3] = fmaf(a1, b.w, acc[1][3]);
            acc[2][0] = fmaf(a2, b.x, acc[2][0]); acc[2][1] = fmaf(a2, b.y, acc[2][1]);
            acc[2][2] = fmaf(a2, b.z, acc[2][2]); acc[2][3] = fmaf(a2, b.w, acc[2][3]);
            acc[3][0] = fmaf(a3, b.x, acc[3][0]); acc[3][1] = fmaf(a3, b.y, acc[3][1]);
            acc[3][2] = fmaf(a3, b.z, acc[3][2]); acc[3][3] = fmaf(a3, b.w, acc[3][3]);
        }
        __syncthreads();
    }
    float4 bv = *(const float4*)(bias + tx * 4);
    #pragma unroll
    for (int i = 0; i < 4; i++) {
        int gm = m0 + ty * 4 + i;
        if (gm < M)
            *(float4*)(Cout + (size_t)gm * OUTD + tx * 4) =
                make_float4(acc[i][0] + bv.x, acc[i][1] + bv.y, acc[i][2] + bv.z, acc[i][3] + bv.w);
    }
}

// ---------------- Fused aggregation: ILP-batched gathers ----------------
// One wave per node. 64 edge indices fetched in one coalesced load, each
// broadcast via v_readlane -> SGPR row base, gathers issued in batches of 8
// independent loads (clamped tail keeps batch depth; masked accumulate).

__device__ __forceinline__ float2 gather_sum(const unsigned int* __restrict__ T,
                                             const int* __restrict__ col,
                                             int s, int e, int lane) {
    float sx = 0.f, sy = 0.f;
    for (int base = s; base < e; base += 64) {
        int m = e - base;
        if (m > 64) m = 64;
        int idx = (base + lane < e) ? col[base + lane] : 0;
        for (int j = 0; j < m; j += 8) {
            unsigned int v[8];
            #pragma unroll
            for (int t = 0; t < 8; t++) {
                int jj = j + t;
                if (jj > m - 1) jj = m - 1;           // clamp: repeat last valid index
                int u = __builtin_amdgcn_readlane(idx, jj);
                v[t] = T[(size_t)u * 64 + lane];
            }
            #pragma unroll
            for (int t = 0; t < 8; t++) {
                unsigned int val = (j + t < m) ? v[t] : 0u;   // uniform mask
                sx += __uint_as_float(val << 16);
                sy += __uint_as_float(val & 0xFFFF0000u);
            }
        }
    }
    return make_float2(sx, sy);
}

__global__ __launch_bounds__(256)
void agg_epilogue(const float* __restrict__ t_self,
                  const unsigned int* __restrict__ t_std2,
                  const unsigned int* __restrict__ t_dts2,
                  const float* __restrict__ bself, const float* __restrict__ bstd,
                  const float* __restrict__ bdts,
                  const int* __restrict__ row_in, const int* __restrict__ col_in,
                  const int* __restrict__ row_out, const int* __restrict__ col_out,
                  const float* __restrict__ alpha_p,
                  unsigned int* __restrict__ h_out, float* __restrict__ jk,
                  int first, int N) {
    int wv = threadIdx.x >> 6;
    int lane = threadIdx.x & 63;
    int n = blockIdx.x * 4 + wv;
    if (n >= N) return;
    float a = alpha_p[0];
    int s_in = row_in[n], e_in = row_in[n + 1];
    int s_out = row_out[n], e_out = row_out[n + 1];

    float2 ain = gather_sum(t_std2, col_in, s_in, e_in, lane);
    float2 aout = gather_sum(t_dts2, col_out, s_out, e_out, lane);

    float win = (1.0f - a) / (float)max(e_in - s_in, 1);
    float wout = a / (float)max(e_out - s_out, 1);
    int j = lane * 2;
    float2 ts = *(const float2*)(t_self + (size_t)n * D + j);
    float bx = bself[j] + (1.0f - a) * bstd[j] + a * bdts[j];
    float by = bself[j + 1] + (1.0f - a) * bstd[j + 1] + a * bdts[j + 1];
    float hx = fmaxf(ts.x + bx + win * ain.x + wout * aout.x, 0.f);
    float hy = fmaxf(ts.y + by + win * ain.y + wout * aout.y, 0.f);
    h_out[(size_t)n * 64 + lane] = (unsigned int)f2bf(hx) | ((unsigned int)f2bf(hy) << 16);
    float2* jp = (float2*)(jk + (size_t)n * D + j);
    if (first) {
        *jp = make_float2(hx, hy);
    } else {
        float2 old = *jp;
        *jp = make_float2(fmaxf(old.x, hx), fmaxf(old.y, hy));
    }
}

// ---------------- launch ----------------

extern "C" void kernel_launch(void* const* d_in, const int* in_sizes, int n_in,
                              void* d_out, int out_size, void* d_ws, size_t ws_size,
                              hipStream_t stream) {
    const float* x     = (const float*)d_in[0];
    const int*   ei    = (const int*)d_in[1];
    const float* Wself = (const float*)d_in[2];
    const float* bself = (const float*)d_in[3];
    const float* Wstd  = (const float*)d_in[4];
    const float* bstd  = (const float*)d_in[5];
    const float* Wdts  = (const float*)d_in[6];
    const float* bdts  = (const float*)d_in[7];
    const float* Wlin  = (const float*)d_in[8];
    const float* blin  = (const float*)d_in[9];
    const float* alpha = (const float*)d_in[10];

    int N = in_sizes[0] / D;   // 50000
    int E = in_sizes[1] / 2;   // 800000

    char* p = (char*)d_ws;
    auto alloc = [&](size_t bytes) {
        char* q = p;
        p += (bytes + 255) & ~(size_t)255;
        return q;
    };
    int* cnt_in  = (int*)alloc((size_t)N * 4);
    int* cnt_out = (int*)alloc((size_t)N * 4);
    int* row_in  = (int*)alloc((size_t)(N + 1) * 4);
    int* row_out = (int*)alloc((size_t)(N + 1) * 4);
    int* col_in  = (int*)alloc((size_t)E * 4);
    int* col_out = (int*)alloc((size_t)E * 4);
    short* xb  = (short*)alloc((size_t)N * D * 2);
    short* hb  = (short*)alloc((size_t)N * D * 2);
    short* wt  = (short*)alloc((size_t)9 * D * D * 2);
    float* t1  = (float*)alloc((size_t)N * D * 4);
    short* t2b = (short*)alloc((size_t)N * D * 2);
    short* t3b = (short*)alloc((size_t)N * D * 2);
    float* jk  = (float*)alloc((size_t)N * D * 4);

    const int* srcp = ei;
    const int* dstp = ei + E;

    hipMemsetAsync(cnt_in, 0, (size_t)N * 4, stream);
    hipMemsetAsync(cnt_out, 0, (size_t)N * 4, stream);
    count_deg<<<ceil_div(E, 256), 256, 0, stream>>>(srcp, dstp, E, cnt_out, cnt_in);
    scan2<<<2, 1024, 0, stream>>>(cnt_in, row_in, cnt_out, row_out, N);
    hipMemsetAsync(cnt_in, 0, (size_t)N * 4, stream);
    hipMemsetAsync(cnt_out, 0, (size_t)N * 4, stream);
    fill_csr<<<ceil_div(E, 256), 256, 0, stream>>>(srcp, dstp, E, row_in, row_out,
                                                   cnt_in, cnt_out, col_in, col_out);

    convert_x<<<ceil_div(N * D / 4, 256), 256, 0, stream>>>(x, (unsigned long long*)xb, N * D / 4);
    convert_wt<<<9, 256, 0, stream>>>(Wself, Wstd, Wdts, wt);

    const short* hin = xb;
    int gm = ceil_div(N, 128);
    for (int l = 0; l < LAYERS; l++) {
        gemm3_bf16<<<dim3(gm, 1, 3), 256, 0, stream>>>(hin, N, wt + (size_t)l * 3 * D * D,
                                                       t1, t2b, t3b);
        agg_epilogue<<<ceil_div(N, 4), 256, 0, stream>>>(t1,
            (const unsigned int*)t2b, (const unsigned int*)t3b,
            bself + (size_t)l * D, bstd + (size_t)l * D, bdts + (size_t)l * D,
            row_in, col_in, row_out, col_out, alpha,
            (unsigned int*)hb, jk, (l == 0) ? 1 : 0, N);
        hin = hb;
    }
    gemm_out<<<ceil_div(N, 64), 256, 0, stream>>>(jk, N, Wlin, blin, (float*)d_out);
}

// Round 4
// 527.765 us; speedup vs baseline: 1.8988x; 1.0950x over previous
//
#include <hip/hip_runtime.h>

#define D 128
#define OUTD 64
#define LAYERS 3

typedef __attribute__((ext_vector_type(8))) short short8;
typedef __attribute__((ext_vector_type(4))) float float4v;

static inline int ceil_div(int a, int b) { return (a + b - 1) / b; }

__device__ __forceinline__ unsigned short f2bf(float f) {
    unsigned int u = __float_as_uint(f);
    unsigned int r = u + 0x7FFFu + ((u >> 16) & 1u);
    return (unsigned short)(r >> 16);
}

// ---------------- CSR build ----------------
// Fused count + rank: the atomicAdd return value IS the edge's slot within
// its node's adjacency list, so fill needs no atomics.

__global__ __launch_bounds__(256)
void rank_count(const int* __restrict__ src, const int* __restrict__ dst, int E,
                int* cnt_out, int* cnt_in,
                int* __restrict__ rank_out, int* __restrict__ rank_in) {
    int e = blockIdx.x * 256 + threadIdx.x;
    if (e < E) {
        rank_in[e]  = atomicAdd(&cnt_in[dst[e]], 1);
        rank_out[e] = atomicAdd(&cnt_out[src[e]], 1);
    }
}

// grid of 2 blocks: block 0 scans cnt_a->row_a, block 1 scans cnt_b->row_b
// (software-pipelined: next chunk's load issues before current chunk's scan)
__global__ __launch_bounds__(1024)
void scan2(const int* __restrict__ cnt_a, int* __restrict__ row_a,
           const int* __restrict__ cnt_b, int* __restrict__ row_b, int n) {
    const int* cnt = blockIdx.x ? cnt_b : cnt_a;
    int* row = blockIdx.x ? row_b : row_a;
    __shared__ int wsum[16];
    __shared__ int chunk_total;
    int lane = threadIdx.x & 63;
    int w = threadIdx.x >> 6;
    int carry = 0;
    int i0 = threadIdx.x;
    int v_next = (i0 < n) ? cnt[i0] : 0;
    for (int base = 0; base < n; base += 1024) {
        int i = base + threadIdx.x;
        int v = v_next;
        int inext = i + 1024;
        v_next = (inext < n) ? cnt[inext] : 0;   // prefetch next chunk
        int x = v;
        #pragma unroll
        for (int off = 1; off < 64; off <<= 1) {
            int y = __shfl_up(x, off, 64);
            if (lane >= off) x += y;
        }
        if (lane == 63) wsum[w] = x;
        __syncthreads();
        if (w == 0 && lane < 16) {
            int s = wsum[lane];
            #pragma unroll
            for (int off = 1; off < 16; off <<= 1) {
                int y = __shfl_up(s, off, 16);
                if (lane >= off) s += y;
            }
            wsum[lane] = s;
            if (lane == 15) chunk_total = s;
        }
        __syncthreads();
        int wpre = (w == 0) ? 0 : wsum[w - 1];
        if (i < n) row[i] = carry + wpre + (x - v);
        carry += chunk_total;
        __syncthreads();
    }
    if (threadIdx.x == 0) row[n] = carry;
}

__global__ __launch_bounds__(256)
void fill_csr(const int* __restrict__ src, const int* __restrict__ dst, int E,
              const int* __restrict__ row_in, const int* __restrict__ row_out,
              const int* __restrict__ rank_in, const int* __restrict__ rank_out,
              int* __restrict__ col_in, int* __restrict__ col_out) {
    int e = blockIdx.x * 256 + threadIdx.x;
    if (e < E) {
        int s = src[e], d = dst[e];
        col_in[row_in[d] + rank_in[e]] = s;
        col_out[row_out[s] + rank_out[e]] = d;
    }
}

// ---------------- converts ----------------

__global__ __launch_bounds__(256)
void convert_x(const float* __restrict__ x, unsigned long long* __restrict__ xb, int n4) {
    int i = blockIdx.x * 256 + threadIdx.x;
    if (i < n4) {
        float4 v = ((const float4*)x)[i];
        unsigned long long p =
            (unsigned long long)f2bf(v.x) |
            ((unsigned long long)f2bf(v.y) << 16) |
            ((unsigned long long)f2bf(v.z) << 32) |
            ((unsigned long long)f2bf(v.w) << 48);
        xb[i] = p;
    }
}

// transpose + convert the 9 per-layer weight matrices to bf16: wt[b][n][k] = W[b][k][n]
__global__ __launch_bounds__(256)
void convert_wt(const float* __restrict__ Wself, const float* __restrict__ Wstd,
                const float* __restrict__ Wdts, short* __restrict__ wt) {
    int b = blockIdx.x;            // 0..8
    int l = b / 3, m = b % 3;
    const float* W = (m == 0 ? Wself : (m == 1 ? Wstd : Wdts)) + (size_t)l * D * D;
    short* o = wt + (size_t)b * D * D;
    for (int idx = threadIdx.x; idx < D * D; idx += 256) {
        int k = idx >> 7, n = idx & 127;
        o[n * D + k] = (short)f2bf(W[idx]);
    }
}

// ---------------- bf16 MFMA GEMM: all three outputs bf16 ----------------

__global__ __launch_bounds__(256)
void gemm3_bf16(const short* __restrict__ Abf, int M,
                const short* __restrict__ wt3,
                short* __restrict__ t1b, short* __restrict__ t2b, short* __restrict__ t3b) {
    __shared__ __align__(16) short As[128][136];
    __shared__ __align__(16) short Bs[128][136];
    int tid = threadIdx.x;
    int m0 = blockIdx.x * 128;
    int z = blockIdx.z;
    const short* Bt = wt3 + (size_t)z * D * D;

    #pragma unroll
    for (int i = 0; i < 8; i++) {
        int v = tid + i * 256;
        int row = v >> 4;
        int c8 = v & 15;
        int gr = m0 + row;
        short8 val = {0, 0, 0, 0, 0, 0, 0, 0};
        if (gr < M) val = *(const short8*)(Abf + (size_t)gr * D + c8 * 8);
        *(short8*)&As[row][c8 * 8] = val;
    }
    #pragma unroll
    for (int i = 0; i < 8; i++) {
        int v = tid + i * 256;
        int row = v >> 4;
        int c8 = v & 15;
        *(short8*)&Bs[row][c8 * 8] = *(const short8*)(Bt + (size_t)row * D + c8 * 8);
    }
    __syncthreads();

    int wave = tid >> 6, lane = tid & 63;
    int quad = lane >> 4, r16 = lane & 15;
    int mrow = wave * 32;

    float4v acc[2][8];
    #pragma unroll
    for (int a = 0; a < 2; a++)
        #pragma unroll
        for (int b = 0; b < 8; b++)
            acc[a][b] = (float4v){0.f, 0.f, 0.f, 0.f};

    #pragma unroll
    for (int kc = 0; kc < 4; kc++) {
        short8 a0 = *(const short8*)&As[mrow + r16][kc * 32 + quad * 8];
        short8 a1 = *(const short8*)&As[mrow + 16 + r16][kc * 32 + quad * 8];
        #pragma unroll
        for (int nt = 0; nt < 8; nt++) {
            short8 b = *(const short8*)&Bs[nt * 16 + r16][kc * 32 + quad * 8];
            acc[0][nt] = __builtin_amdgcn_mfma_f32_16x16x32_bf16(a0, b, acc[0][nt], 0, 0, 0);
            acc[1][nt] = __builtin_amdgcn_mfma_f32_16x16x32_bf16(a1, b, acc[1][nt], 0, 0, 0);
        }
    }

    short* Cb = (z == 0) ? t1b : ((z == 1) ? t2b : t3b);
    #pragma unroll
    for (int rt = 0; rt < 2; rt++)
        #pragma unroll
        for (int nt = 0; nt < 8; nt++)
            #pragma unroll
            for (int reg = 0; reg < 4; reg++) {
                int row = m0 + mrow + rt * 16 + quad * 4 + reg;
                if (row < M) Cb[(size_t)row * D + nt * 16 + r16] = (short)f2bf(acc[rt][nt][reg]);
            }
}

// ---------------- Final GEMM: out = jk @ Wlin + blin (fp32 SIMT) ----------------

__global__ __launch_bounds__(256)
void gemm_out(const float* __restrict__ A, int M, const float* __restrict__ W,
              const float* __restrict__ bias, float* __restrict__ Cout) {
    __shared__ float As[64][68];
    __shared__ float Bs[64][68];
    int tid = threadIdx.x;
    int tx = tid & 15, ty = tid >> 4;
    int m0 = blockIdx.x * 64;

    float acc[4][4] = {{0.f}};
    int r = tid >> 4;
    int kq = tid & 15;

    for (int kt = 0; kt < D; kt += 64) {
        #pragma unroll
        for (int i = 0; i < 4; i++) {
            int row = r + i * 16;
            int gm = m0 + row;
            float4 v = make_float4(0.f, 0.f, 0.f, 0.f);
            if (gm < M) v = *(const float4*)(A + (size_t)gm * D + kt + kq * 4);
            *(float4*)&As[row][kq * 4] = v;
        }
        #pragma unroll
        for (int i = 0; i < 4; i++) {
            int k = r + i * 16;
            *(float4*)&Bs[k][kq * 4] = *(const float4*)(W + (size_t)(kt + k) * OUTD + kq * 4);
        }
        __syncthreads();
        #pragma unroll 8
        for (int k = 0; k < 64; k++) {
            float4 b = *(const float4*)&Bs[k][tx * 4];
            float a0 = As[ty * 4 + 0][k];
            float a1 = As[ty * 4 + 1][k];
            float a2 = As[ty * 4 + 2][k];
            float a3 = As[ty * 4 + 3][k];
            acc[0][0] = fmaf(a0, b.x, acc[0][0]); acc[0][1] = fmaf(a0, b.y, acc[0][1]);
            acc[0][2] = fmaf(a0, b.z, acc[0][2]); acc[0][3] = fmaf(a0, b.w, acc[0][3]);
            acc[1][0] = fmaf(a1, b.x, acc[1][0]); acc[1][1] = fmaf(a1, b.y, acc[1][1]);
            acc[1][2] = fmaf(a1, b.z, acc[1][2]); acc[1][3] = fmaf(a1, b.w, acc[1][3]);
            acc[2][0] = fmaf(a2, b.x, acc[2][0]); acc[2][1] = fmaf(a2, b.y, acc[2][1]);
            acc[2][2] = fmaf(a2, b.z, acc[2][2]); acc[2][3] = fmaf(a2, b.w, acc[2][3]);
            acc[3][0] = fmaf(a3, b.x, acc[3][0]); acc[3][1] = fmaf(a3, b.y, acc[3][1]);
            acc[3][2] = fmaf(a3, b.z, acc[3][2]); acc[3][3] = fmaf(a3, b.w, acc[3][3]);
        }
        __syncthreads();
    }
    float4 bv = *(const float4*)(bias + tx * 4);
    #pragma unroll
    for (int i = 0; i < 4; i++) {
        int gm = m0 + ty * 4 + i;
        if (gm < M)
            *(float4*)(Cout + (size_t)gm * OUTD + tx * 4) =
                make_float4(acc[i][0] + bv.x, acc[i][1] + bv.y, acc[i][2] + bv.z, acc[i][3] + bv.w);
    }
}

// ---------------- Fused aggregation: dual-stream, 16-deep ILP gathers ----------------
// One wave per node. In- and out-edge streams interleaved: up to 32 outstanding
// gathers per wave. Edge indices broadcast via readlane (SGPR base gathers).

__global__ __launch_bounds__(256)
void agg_epilogue(const unsigned int* __restrict__ t1b,
                  const unsigned int* __restrict__ t2b,
                  const unsigned int* __restrict__ t3b,
                  const float* __restrict__ bself, const float* __restrict__ bstd,
                  const float* __restrict__ bdts,
                  const int* __restrict__ row_in, const int* __restrict__ col_in,
                  const int* __restrict__ row_out, const int* __restrict__ col_out,
                  const float* __restrict__ alpha_p,
                  unsigned int* __restrict__ h_out, float* __restrict__ jk,
                  int first, int N) {
    int wv = threadIdx.x >> 6;
    int lane = threadIdx.x & 63;
    int n = blockIdx.x * 4 + wv;
    if (n >= N) return;
    float a = alpha_p[0];
    int s_in = row_in[n], e_in = row_in[n + 1];
    int s_out = row_out[n], e_out = row_out[n + 1];

    float ax = 0.f, ay = 0.f, ox = 0.f, oy = 0.f;
    int pin = s_in, pout = s_out;
    while (pin < e_in || pout < e_out) {
        int m_in = e_in - pin;   if (m_in > 64) m_in = 64;
        int m_out = e_out - pout; if (m_out > 64) m_out = 64;
        int idxi = (pin + lane < e_in) ? col_in[pin + lane] : 0;
        int idxo = (pout + lane < e_out) ? col_out[pout + lane] : 0;
        int mmax = m_in > m_out ? m_in : m_out;
        for (int j = 0; j < mmax; j += 16) {
            unsigned int vi[16], vo[16];
            if (j < m_in) {
                #pragma unroll
                for (int t = 0; t < 16; t++) {
                    int jj = j + t;
                    if (jj > m_in - 1) jj = m_in - 1;
                    int u = __builtin_amdgcn_readlane(idxi, jj);
                    vi[t] = t2b[(size_t)u * 64 + lane];
                }
            }
            if (j < m_out) {
                #pragma unroll
                for (int t = 0; t < 16; t++) {
                    int jj = j + t;
                    if (jj > m_out - 1) jj = m_out - 1;
                    int u = __builtin_amdgcn_readlane(idxo, jj);
                    vo[t] = t3b[(size_t)u * 64 + lane];
                }
            }
            if (j < m_in) {
                #pragma unroll
                for (int t = 0; t < 16; t++) {
                    unsigned int val = (j + t < m_in) ? vi[t] : 0u;
                    ax += __uint_as_float(val << 16);
                    ay += __uint_as_float(val & 0xFFFF0000u);
                }
            }
            if (j < m_out) {
                #pragma unroll
                for (int t = 0; t < 16; t++) {
                    unsigned int val = (j + t < m_out) ? vo[t] : 0u;
                    ox += __uint_as_float(val << 16);
                    oy += __uint_as_float(val & 0xFFFF0000u);
                }
            }
        }
        pin += 64; pout += 64;
    }

    float win = (1.0f - a) / (float)max(e_in - s_in, 1);
    float wout = a / (float)max(e_out - s_out, 1);
    int j = lane * 2;
    unsigned int tsv = t1b[(size_t)n * 64 + lane];
    float tsx = __uint_as_float(tsv << 16);
    float tsy = __uint_as_float(tsv & 0xFFFF0000u);
    float bx = bself[j] + (1.0f - a) * bstd[j] + a * bdts[j];
    float by = bself[j + 1] + (1.0f - a) * bstd[j + 1] + a * bdts[j + 1];
    float hx = fmaxf(tsx + bx + win * ax + wout * ox, 0.f);
    float hy = fmaxf(tsy + by + win * ay + wout * oy, 0.f);
    h_out[(size_t)n * 64 + lane] = (unsigned int)f2bf(hx) | ((unsigned int)f2bf(hy) << 16);
    float2* jp = (float2*)(jk + (size_t)n * D + j);
    if (first) {
        *jp = make_float2(hx, hy);
    } else {
        float2 old = *jp;
        *jp = make_float2(fmaxf(old.x, hx), fmaxf(old.y, hy));
    }
}

// ---------------- launch ----------------

extern "C" void kernel_launch(void* const* d_in, const int* in_sizes, int n_in,
                              void* d_out, int out_size, void* d_ws, size_t ws_size,
                              hipStream_t stream) {
    const float* x     = (const float*)d_in[0];
    const int*   ei    = (const int*)d_in[1];
    const float* Wself = (const float*)d_in[2];
    const float* bself = (const float*)d_in[3];
    const float* Wstd  = (const float*)d_in[4];
    const float* bstd  = (const float*)d_in[5];
    const float* Wdts  = (const float*)d_in[6];
    const float* bdts  = (const float*)d_in[7];
    const float* Wlin  = (const float*)d_in[8];
    const float* blin  = (const float*)d_in[9];
    const float* alpha = (const float*)d_in[10];

    int N = in_sizes[0] / D;   // 50000
    int E = in_sizes[1] / 2;   // 800000

    char* p = (char*)d_ws;
    auto alloc = [&](size_t bytes) {
        char* q = p;
        p += (bytes + 255) & ~(size_t)255;
        return q;
    };
    int* cnt_in   = (int*)alloc((size_t)N * 4);
    int* cnt_out  = (int*)alloc((size_t)N * 4);
    int* row_in   = (int*)alloc((size_t)(N + 1) * 4);
    int* row_out  = (int*)alloc((size_t)(N + 1) * 4);
    int* rank_in  = (int*)alloc((size_t)E * 4);
    int* rank_out = (int*)alloc((size_t)E * 4);
    int* col_in   = (int*)alloc((size_t)E * 4);
    int* col_out  = (int*)alloc((size_t)E * 4);
    short* xb  = (short*)alloc((size_t)N * D * 2);
    short* hb  = (short*)alloc((size_t)N * D * 2);
    short* wt  = (short*)alloc((size_t)9 * D * D * 2);
    short* t1b = (short*)alloc((size_t)N * D * 2);
    short* t2b = (short*)alloc((size_t)N * D * 2);
    short* t3b = (short*)alloc((size_t)N * D * 2);
    float* jk  = (float*)alloc((size_t)N * D * 4);

    const int* srcp = ei;
    const int* dstp = ei + E;

    hipMemsetAsync(cnt_in, 0, (size_t)N * 4, stream);
    hipMemsetAsync(cnt_out, 0, (size_t)N * 4, stream);
    rank_count<<<ceil_div(E, 256), 256, 0, stream>>>(srcp, dstp, E, cnt_out, cnt_in,
                                                     rank_out, rank_in);
    scan2<<<2, 1024, 0, stream>>>(cnt_in, row_in, cnt_out, row_out, N);
    fill_csr<<<ceil_div(E, 256), 256, 0, stream>>>(srcp, dstp, E, row_in, row_out,
                                                   rank_in, rank_out, col_in, col_out);

    convert_x<<<ceil_div(N * D / 4, 256), 256, 0, stream>>>(x, (unsigned long long*)xb, N * D / 4);
    convert_wt<<<9, 256, 0, stream>>>(Wself, Wstd, Wdts, wt);

    const short* hin = xb;
    int gm = ceil_div(N, 128);
    for (int l = 0; l < LAYERS; l++) {
        gemm3_bf16<<<dim3(gm, 1, 3), 256, 0, stream>>>(hin, N, wt + (size_t)l * 3 * D * D,
                                                       t1b, t2b, t3b);
        agg_epilogue<<<ceil_div(N, 4), 256, 0, stream>>>(
            (const unsigned int*)t1b, (const unsigned int*)t2b, (const unsigned int*)t3b,
            bself + (size_t)l * D, bstd + (size_t)l * D, bdts + (size_t)l * D,
            row_in, col_in, row_out, col_out, alpha,
            (unsigned int*)hb, jk, (l == 0) ? 1 : 0, N);
        hin = hb;
    }
    gemm_out<<<ceil_div(N, 64), 256, 0, stream>>>(jk, N, Wlin, blin, (float*)d_out);
}

// Round 5
// 518.251 us; speedup vs baseline: 1.9337x; 1.0184x over previous
//
#include <hip/hip_runtime.h>

#define D 128
#define OUTD 64
#define LAYERS 3

typedef __attribute__((ext_vector_type(8))) short short8;
typedef __attribute__((ext_vector_type(4))) float float4v;
typedef unsigned int uint32;

static inline int ceil_div(int a, int b) { return (a + b - 1) / b; }

__device__ __forceinline__ unsigned short f2bf(float f) {
    unsigned int u = __float_as_uint(f);
    unsigned int r = u + 0x7FFFu + ((u >> 16) & 1u);
    return (unsigned short)(r >> 16);
}

// ---------------- CSR build ----------------

__global__ __launch_bounds__(256)
void rank_count(const int* __restrict__ src, const int* __restrict__ dst, int E,
                int* cnt_out, int* cnt_in,
                int* __restrict__ rank_out, int* __restrict__ rank_in) {
    int e = blockIdx.x * 256 + threadIdx.x;
    if (e < E) {
        rank_in[e]  = atomicAdd(&cnt_in[dst[e]], 1);
        rank_out[e] = atomicAdd(&cnt_out[src[e]], 1);
    }
}

__global__ __launch_bounds__(1024)
void scan2(const int* __restrict__ cnt_a, int* __restrict__ row_a,
           const int* __restrict__ cnt_b, int* __restrict__ row_b, int n) {
    const int* cnt = blockIdx.x ? cnt_b : cnt_a;
    int* row = blockIdx.x ? row_b : row_a;
    __shared__ int wsum[16];
    __shared__ int chunk_total;
    int lane = threadIdx.x & 63;
    int w = threadIdx.x >> 6;
    int carry = 0;
    int i0 = threadIdx.x;
    int v_next = (i0 < n) ? cnt[i0] : 0;
    for (int base = 0; base < n; base += 1024) {
        int i = base + threadIdx.x;
        int v = v_next;
        int inext = i + 1024;
        v_next = (inext < n) ? cnt[inext] : 0;
        int x = v;
        #pragma unroll
        for (int off = 1; off < 64; off <<= 1) {
            int y = __shfl_up(x, off, 64);
            if (lane >= off) x += y;
        }
        if (lane == 63) wsum[w] = x;
        __syncthreads();
        if (w == 0 && lane < 16) {
            int s = wsum[lane];
            #pragma unroll
            for (int off = 1; off < 16; off <<= 1) {
                int y = __shfl_up(s, off, 16);
                if (lane >= off) s += y;
            }
            wsum[lane] = s;
            if (lane == 15) chunk_total = s;
        }
        __syncthreads();
        int wpre = (w == 0) ? 0 : wsum[w - 1];
        if (i < n) row[i] = carry + wpre + (x - v);
        carry += chunk_total;
        __syncthreads();
    }
    if (threadIdx.x == 0) row[n] = carry;
}

// XCD-partitioned fill: block group (blockIdx&7) writes only its 1/8 node range,
// so random col-stores stay in one XCD's L2 (no cross-die line bouncing).
// Correctness does not depend on the block->XCD mapping (perf heuristic only).
__global__ __launch_bounds__(256)
void fill_csr_xcd(const int* __restrict__ src, const int* __restrict__ dst, int E,
                  const int* __restrict__ row_in, const int* __restrict__ row_out,
                  const int* __restrict__ rank_in, const int* __restrict__ rank_out,
                  int* __restrict__ col_in, int* __restrict__ col_out, int N) {
    int xcd = blockIdx.x & 7;
    int chunk = blockIdx.x >> 3;
    int nchunks = gridDim.x >> 3;
    int lo = (int)((long long)xcd * N / 8);
    int hi = (int)((long long)(xcd + 1) * N / 8);
    int stride = nchunks * 256;
    for (int e = chunk * 256 + threadIdx.x; e < E; e += stride) {
        int s = src[e], d = dst[e];
        if (d >= lo && d < hi) col_in[row_in[d] + rank_in[e]] = s;
        if (s >= lo && s < hi) col_out[row_out[s] + rank_out[e]] = d;
    }
}

// ---------------- converts ----------------

__global__ __launch_bounds__(256)
void convert_x(const float* __restrict__ x, unsigned long long* __restrict__ xb, int n4) {
    int i = blockIdx.x * 256 + threadIdx.x;
    if (i < n4) {
        float4 v = ((const float4*)x)[i];
        unsigned long long p =
            (unsigned long long)f2bf(v.x) |
            ((unsigned long long)f2bf(v.y) << 16) |
            ((unsigned long long)f2bf(v.z) << 32) |
            ((unsigned long long)f2bf(v.w) << 48);
        xb[i] = p;
    }
}

// b<9: transpose+convert the 9 layer weights; b==9: transpose+convert Wlin;
// b==10: combined biases bcomb[l][j] = bself + (1-a)*bstd + a*bdts
__global__ __launch_bounds__(256)
void convert_wt(const float* __restrict__ Wself, const float* __restrict__ Wstd,
                const float* __restrict__ Wdts, const float* __restrict__ Wlin,
                const float* __restrict__ bself, const float* __restrict__ bstd,
                const float* __restrict__ bdts, const float* __restrict__ alpha_p,
                short* __restrict__ wt, short* __restrict__ wlt,
                float* __restrict__ bcomb) {
    int b = blockIdx.x;
    if (b < 9) {
        int l = b / 3, m = b % 3;
        const float* W = (m == 0 ? Wself : (m == 1 ? Wstd : Wdts)) + (size_t)l * D * D;
        short* o = wt + (size_t)b * D * D;
        for (int idx = threadIdx.x; idx < D * D; idx += 256) {
            int k = idx >> 7, n = idx & 127;
            o[n * D + k] = (short)f2bf(W[idx]);
        }
    } else if (b == 9) {
        for (int idx = threadIdx.x; idx < D * OUTD; idx += 256) {
            int k = idx >> 6, n = idx & 63;
            wlt[n * D + k] = (short)f2bf(Wlin[idx]);
        }
    } else {
        float a = alpha_p[0];
        for (int i = threadIdx.x; i < LAYERS * D; i += 256) {
            bcomb[i] = bself[i] + (1.0f - a) * bstd[i] + a * bdts[i];
        }
    }
}

// ---------------- bf16 MFMA GEMM: all three outputs bf16 ----------------

__global__ __launch_bounds__(256)
void gemm3_bf16(const short* __restrict__ Abf, int M,
                const short* __restrict__ wt3,
                short* __restrict__ t1b, short* __restrict__ t2b, short* __restrict__ t3b) {
    __shared__ __align__(16) short As[128][136];
    __shared__ __align__(16) short Bs[128][136];
    int tid = threadIdx.x;
    int m0 = blockIdx.x * 128;
    int z = blockIdx.z;
    const short* Bt = wt3 + (size_t)z * D * D;

    #pragma unroll
    for (int i = 0; i < 8; i++) {
        int v = tid + i * 256;
        int row = v >> 4;
        int c8 = v & 15;
        int gr = m0 + row;
        short8 val = {0, 0, 0, 0, 0, 0, 0, 0};
        if (gr < M) val = *(const short8*)(Abf + (size_t)gr * D + c8 * 8);
        *(short8*)&As[row][c8 * 8] = val;
    }
    #pragma unroll
    for (int i = 0; i < 8; i++) {
        int v = tid + i * 256;
        int row = v >> 4;
        int c8 = v & 15;
        *(short8*)&Bs[row][c8 * 8] = *(const short8*)(Bt + (size_t)row * D + c8 * 8);
    }
    __syncthreads();

    int wave = tid >> 6, lane = tid & 63;
    int quad = lane >> 4, r16 = lane & 15;
    int mrow = wave * 32;

    float4v acc[2][8];
    #pragma unroll
    for (int a = 0; a < 2; a++)
        #pragma unroll
        for (int b = 0; b < 8; b++)
            acc[a][b] = (float4v){0.f, 0.f, 0.f, 0.f};

    #pragma unroll
    for (int kc = 0; kc < 4; kc++) {
        short8 a0 = *(const short8*)&As[mrow + r16][kc * 32 + quad * 8];
        short8 a1 = *(const short8*)&As[mrow + 16 + r16][kc * 32 + quad * 8];
        #pragma unroll
        for (int nt = 0; nt < 8; nt++) {
            short8 b = *(const short8*)&Bs[nt * 16 + r16][kc * 32 + quad * 8];
            acc[0][nt] = __builtin_amdgcn_mfma_f32_16x16x32_bf16(a0, b, acc[0][nt], 0, 0, 0);
            acc[1][nt] = __builtin_amdgcn_mfma_f32_16x16x32_bf16(a1, b, acc[1][nt], 0, 0, 0);
        }
    }

    short* Cb = (z == 0) ? t1b : ((z == 1) ? t2b : t3b);
    #pragma unroll
    for (int rt = 0; rt < 2; rt++)
        #pragma unroll
        for (int nt = 0; nt < 8; nt++)
            #pragma unroll
            for (int reg = 0; reg < 4; reg++) {
                int row = m0 + mrow + rt * 16 + quad * 4 + reg;
                if (row < M) Cb[(size_t)row * D + nt * 16 + r16] = (short)f2bf(acc[rt][nt][reg]);
            }
}

// ---------------- Final GEMM (MFMA): out = jkb(bf16) @ wlt^T + blin ----------------

__global__ __launch_bounds__(256)
void gemm_out_mfma(const short* __restrict__ jkb, int M, const short* __restrict__ wlt,
                   const float* __restrict__ blin, float* __restrict__ Cout) {
    __shared__ __align__(16) short As[128][136];
    __shared__ __align__(16) short Bs[64][136];
    int tid = threadIdx.x;
    int m0 = blockIdx.x * 128;

    #pragma unroll
    for (int i = 0; i < 8; i++) {
        int v = tid + i * 256;
        int row = v >> 4;
        int c8 = v & 15;
        int gr = m0 + row;
        short8 val = {0, 0, 0, 0, 0, 0, 0, 0};
        if (gr < M) val = *(const short8*)(jkb + (size_t)gr * D + c8 * 8);
        *(short8*)&As[row][c8 * 8] = val;
    }
    #pragma unroll
    for (int i = 0; i < 4; i++) {
        int v = tid + i * 256;
        int row = v >> 4;
        int c8 = v & 15;
        *(short8*)&Bs[row][c8 * 8] = *(const short8*)(wlt + (size_t)row * D + c8 * 8);
    }
    __syncthreads();

    int wave = tid >> 6, lane = tid & 63;
    int quad = lane >> 4, r16 = lane & 15;
    int mrow = wave * 32;

    float4v acc[2][4];
    #pragma unroll
    for (int a = 0; a < 2; a++)
        #pragma unroll
        for (int b = 0; b < 4; b++)
            acc[a][b] = (float4v){0.f, 0.f, 0.f, 0.f};

    #pragma unroll
    for (int kc = 0; kc < 4; kc++) {
        short8 a0 = *(const short8*)&As[mrow + r16][kc * 32 + quad * 8];
        short8 a1 = *(const short8*)&As[mrow + 16 + r16][kc * 32 + quad * 8];
        #pragma unroll
        for (int nt = 0; nt < 4; nt++) {
            short8 b = *(const short8*)&Bs[nt * 16 + r16][kc * 32 + quad * 8];
            acc[0][nt] = __builtin_amdgcn_mfma_f32_16x16x32_bf16(a0, b, acc[0][nt], 0, 0, 0);
            acc[1][nt] = __builtin_amdgcn_mfma_f32_16x16x32_bf16(a1, b, acc[1][nt], 0, 0, 0);
        }
    }

    #pragma unroll
    for (int rt = 0; rt < 2; rt++)
        #pragma unroll
        for (int nt = 0; nt < 4; nt++)
            #pragma unroll
            for (int reg = 0; reg < 4; reg++) {
                int row = m0 + mrow + rt * 16 + quad * 4 + reg;
                int col = nt * 16 + r16;
                if (row < M) Cout[(size_t)row * OUTD + col] = acc[rt][nt][reg] + blin[col];
            }
}

// ---------------- Fused aggregation: exact 8-deep batches, dual-stream ----------------
// One wave per node. Full batches of 8 gathers run with NO masking/clamping;
// the <=7-edge tail is the only masked work. Saves the ~47% clamped-gather
// waste of the fixed-depth scheme at mean degree 16.

__global__ __launch_bounds__(256)
void agg_epilogue(const uint32* __restrict__ t1b,
                  const uint32* __restrict__ t2b,
                  const uint32* __restrict__ t3b,
                  const float* __restrict__ bcomb,
                  const int* __restrict__ row_in, const int* __restrict__ col_in,
                  const int* __restrict__ row_out, const int* __restrict__ col_out,
                  const float* __restrict__ alpha_p,
                  uint32* __restrict__ h_out, uint32* __restrict__ jkb,
                  int first, int N) {
    int wv = threadIdx.x >> 6;
    int lane = threadIdx.x & 63;
    int n = blockIdx.x * 4 + wv;
    if (n >= N) return;
    float a = alpha_p[0];
    int s_in = row_in[n], e_in = row_in[n + 1];
    int s_out = row_out[n], e_out = row_out[n + 1];
    int din = e_in - s_in, dout = e_out - s_out;

    float ax = 0.f, ay = 0.f, ox = 0.f, oy = 0.f;
    int pin = s_in, pout = s_out;
    while (pin < e_in || pout < e_out) {
        int m_in = e_in - pin;   if (m_in > 64) m_in = 64;   if (m_in < 0) m_in = 0;
        int m_out = e_out - pout; if (m_out > 64) m_out = 64; if (m_out < 0) m_out = 0;
        int idxi = (lane < m_in) ? col_in[pin + lane] : 0;
        int idxo = (lane < m_out) ? col_out[pout + lane] : 0;
        int fi = m_in & ~7, fo = m_out & ~7;
        int ji = 0, jo = 0;
        while (ji < fi || jo < fo) {
            uint32 vi[8], vo[8];
            bool di = ji < fi, dw = jo < fo;
            if (di) {
                #pragma unroll
                for (int t = 0; t < 8; t++) {
                    int u = __builtin_amdgcn_readlane(idxi, ji + t);
                    vi[t] = t2b[(size_t)u * 64 + lane];
                }
            }
            if (dw) {
                #pragma unroll
                for (int t = 0; t < 8; t++) {
                    int u = __builtin_amdgcn_readlane(idxo, jo + t);
                    vo[t] = t3b[(size_t)u * 64 + lane];
                }
            }
            if (di) {
                #pragma unroll
                for (int t = 0; t < 8; t++) {
                    ax += __uint_as_float(vi[t] << 16);
                    ay += __uint_as_float(vi[t] & 0xFFFF0000u);
                }
                ji += 8;
            }
            if (dw) {
                #pragma unroll
                for (int t = 0; t < 8; t++) {
                    ox += __uint_as_float(vo[t] << 16);
                    oy += __uint_as_float(vo[t] & 0xFFFF0000u);
                }
                jo += 8;
            }
        }
        int ri = m_in - fi, ro = m_out - fo;   // 0..7
        if (ri | ro) {
            uint32 vi[8], vo[8];
            #pragma unroll
            for (int t = 0; t < 8; t++) { vi[t] = 0u; vo[t] = 0u; }
            #pragma unroll
            for (int t = 0; t < 7; t++) {
                if (t < ri) {
                    int u = __builtin_amdgcn_readlane(idxi, fi + t);
                    vi[t] = t2b[(size_t)u * 64 + lane];
                }
            }
            #pragma unroll
            for (int t = 0; t < 7; t++) {
                if (t < ro) {
                    int u = __builtin_amdgcn_readlane(idxo, fo + t);
                    vo[t] = t3b[(size_t)u * 64 + lane];
                }
            }
            #pragma unroll
            for (int t = 0; t < 7; t++) {
                ax += __uint_as_float(vi[t] << 16);
                ay += __uint_as_float(vi[t] & 0xFFFF0000u);
                ox += __uint_as_float(vo[t] << 16);
                oy += __uint_as_float(vo[t] & 0xFFFF0000u);
            }
        }
        pin += m_in; pout += m_out;
    }

    float win = (1.0f - a) / (float)max(din, 1);
    float wout = a / (float)max(dout, 1);
    uint32 tsv = t1b[(size_t)n * 64 + lane];
    float2 bc = *(const float2*)(bcomb + lane * 2);
    float hx = fmaxf(__uint_as_float(tsv << 16) + bc.x + win * ax + wout * ox, 0.f);
    float hy = fmaxf(__uint_as_float(tsv & 0xFFFF0000u) + bc.y + win * ay + wout * oy, 0.f);
    uint32 hp = (uint32)f2bf(hx) | ((uint32)f2bf(hy) << 16);
    if (h_out) h_out[(size_t)n * 64 + lane] = hp;
    size_t ji2 = (size_t)n * 64 + lane;
    if (first) {
        jkb[ji2] = hp;
    } else {
        // relu'd bf16 values are non-negative -> monotone as u16; per-half uint max
        uint32 old = jkb[ji2];
        uint32 lo_ = max(old & 0xFFFFu, hp & 0xFFFFu);
        uint32 hi_ = max(old & 0xFFFF0000u, hp & 0xFFFF0000u);
        jkb[ji2] = lo_ | hi_;
    }
}

// ---------------- launch ----------------

extern "C" void kernel_launch(void* const* d_in, const int* in_sizes, int n_in,
                              void* d_out, int out_size, void* d_ws, size_t ws_size,
                              hipStream_t stream) {
    const float* x     = (const float*)d_in[0];
    const int*   ei    = (const int*)d_in[1];
    const float* Wself = (const float*)d_in[2];
    const float* bself = (const float*)d_in[3];
    const float* Wstd  = (const float*)d_in[4];
    const float* bstd  = (const float*)d_in[5];
    const float* Wdts  = (const float*)d_in[6];
    const float* bdts  = (const float*)d_in[7];
    const float* Wlin  = (const float*)d_in[8];
    const float* blin  = (const float*)d_in[9];
    const float* alpha = (const float*)d_in[10];

    int N = in_sizes[0] / D;   // 50000
    int E = in_sizes[1] / 2;   // 800000

    char* p = (char*)d_ws;
    auto alloc = [&](size_t bytes) {
        char* q = p;
        p += (bytes + 255) & ~(size_t)255;
        return q;
    };
    int* cnt_in   = (int*)alloc((size_t)N * 4);
    int* cnt_out  = (int*)alloc((size_t)N * 4);
    int* row_in   = (int*)alloc((size_t)(N + 1) * 4);
    int* row_out  = (int*)alloc((size_t)(N + 1) * 4);
    int* rank_in  = (int*)alloc((size_t)E * 4);
    int* rank_out = (int*)alloc((size_t)E * 4);
    int* col_in   = (int*)alloc((size_t)E * 4);
    int* col_out  = (int*)alloc((size_t)E * 4);
    short* xb   = (short*)alloc((size_t)N * D * 2);
    short* hb   = (short*)alloc((size_t)N * D * 2);
    short* wt   = (short*)alloc((size_t)9 * D * D * 2);
    short* wlt  = (short*)alloc((size_t)D * OUTD * 2);
    float* bcomb = (float*)alloc((size_t)LAYERS * D * 4);
    short* t1b  = (short*)alloc((size_t)N * D * 2);
    short* t2b  = (short*)alloc((size_t)N * D * 2);
    short* t3b  = (short*)alloc((size_t)N * D * 2);
    short* jkb  = (short*)alloc((size_t)N * D * 2);

    const int* srcp = ei;
    const int* dstp = ei + E;

    hipMemsetAsync(cnt_in, 0, (size_t)N * 4, stream);
    hipMemsetAsync(cnt_out, 0, (size_t)N * 4, stream);
    rank_count<<<ceil_div(E, 256), 256, 0, stream>>>(srcp, dstp, E, cnt_out, cnt_in,
                                                     rank_out, rank_in);
    scan2<<<2, 1024, 0, stream>>>(cnt_in, row_in, cnt_out, row_out, N);
    fill_csr_xcd<<<1024, 256, 0, stream>>>(srcp, dstp, E, row_in, row_out,
                                           rank_in, rank_out, col_in, col_out, N);

    convert_x<<<ceil_div(N * D / 4, 256), 256, 0, stream>>>(x, (unsigned long long*)xb, N * D / 4);
    convert_wt<<<11, 256, 0, stream>>>(Wself, Wstd, Wdts, Wlin, bself, bstd, bdts, alpha,
                                       wt, wlt, bcomb);

    const short* hin = xb;
    int gm = ceil_div(N, 128);
    for (int l = 0; l < LAYERS; l++) {
        gemm3_bf16<<<dim3(gm, 1, 3), 256, 0, stream>>>(hin, N, wt + (size_t)l * 3 * D * D,
                                                       t1b, t2b, t3b);
        agg_epilogue<<<ceil_div(N, 4), 256, 0, stream>>>(
            (const uint32*)t1b, (const uint32*)t2b, (const uint32*)t3b,
            bcomb + (size_t)l * D,
            row_in, col_in, row_out, col_out, alpha,
            (l == LAYERS - 1) ? nullptr : (uint32*)hb, (uint32*)jkb,
            (l == 0) ? 1 : 0, N);
        hin = hb;
    }
    gemm_out_mfma<<<gm, 256, 0, stream>>>(jkb, N, wlt, blin, (float*)d_out);
}